// Round 13
// baseline (332.264 us; speedup 1.0000x reference)
//
#include <hip/hip_runtime.h>
#include <math.h>

#define N_TOTAL    68096
#define NUM_INPUT  2048
#define NUM_OUTPUT 512
#define OUT_START  67584   // NUM_INPUT + NUM_HIDDEN
#define N_TGT      66048   // N_TOTAL - NUM_INPUT
#define NUM_HIDDEN 65536
#define FB_WORDS   2048    // 65536 hidden bits
#define FAN_OUT    256
#define THRESH     0.3f
#define T_MAX      50
#define T_BIG      12      // steps [0, T_BIG) multi-launch; rest in tail_k
#define BM_WORDS   2064    // ceil(66048 / 32)
#define LIST_CAP   12288

#define QTR_SZ     16512   // N_TGT / 4 targets per quarter
#define N_CHUNK    128     // max frontier chunks in dense mode
#define DENSE_K    6000    // dense iff fcnt * unfired >= DENSE_K * NUM_HIDDEN
                           // (=> strict subset of r9's fcnt>=6000 dense set;
                           //  r12's 2000 made mid-size steps dense: -50us)

// Dead-state optimization: once a HIDDEN neuron fires, its pot/last_update
// can never influence the outputs (out_times + output pot). Edges into
// fired-hidden targets are skipped; fired-hidden targets are skipped in
// update sweeps. fbits = hidden-fired bitmap. cnt[2]/cnt[3] = ping-pong
// count of UNFIRED hidden neurons, gating dense vs sparse on LIVE edges.
// rep partials deliberately CACHED (nontemporal forced HBM latency, +70us).

__device__ __forceinline__ int calc_chunks(int fcnt) {
    int c = fcnt >> 7;                           // ~128 sources per chunk
    if (c < 1) c = 1;
    if (c > N_CHUNK) c = N_CHUNK;
    return c;
}

__device__ __forceinline__ bool gate_dense(int fcnt, int unfired) {
    return (long long)fcnt * unfired >= (long long)DENSE_K * NUM_HIDDEN;
}

// ---------------------------------------------------------------------------
// init: decay table, state arrays, fbits, frontier0 from input spikes.
// Input-bool dtype (int32/float32/uint8) detected per-block (2 KB scan).
// ---------------------------------------------------------------------------
__global__ __launch_bounds__(256) void init_k(
    const unsigned int* __restrict__ in0,
    float* pot, float* acc, int* last_up, unsigned char* fired,
    int* frontier0, int* cnt, float* out_f, float* decay_tab,
    unsigned* fbits)
{
    __shared__ int sF, sG;
    const int tid = threadIdx.x;
    if (tid == 0) { sF = 0; sG = 0; }
    __syncthreads();
    for (int k = tid; k < 512; k += 256) {       // 2048 bytes: safe all modes
        unsigned int v = in0[k];
        if (v == 0x3F800000u) atomicAdd(&sF, 1);
        else if (v > 1u)      sG = 1;            // benign race
    }
    __syncthreads();
    const int mode = (sF >= 8) ? 1 : (sG ? 2 : 0);

    const int i = blockIdx.x * 256 + tid;
    const int lane = tid & 63;
    if (i == 0) cnt[2] = NUM_HIDDEN;             // unfired-hidden (slot t=0)
    if (i <= T_MAX) {
        float base = expf(-0.05f);               // exact validated path
        decay_tab[i] = (float)pow((double)base, (double)i);
    }
    if (i < NUM_OUTPUT) out_f[i] = -1.0f;
    if (i < FB_WORDS)   fbits[i] = 0u;
    bool want = false;
    if (i < N_TOTAL) {
        pot[i] = 0.0f;
        acc[i] = 0.0f;
        last_up[i] = 0;
        bool s = false;
        if (i < NUM_INPUT) {
            if (mode == 0)      s = ((const int*)in0)[i] != 0;
            else if (mode == 1) s = ((const float*)in0)[i] != 0.0f;
            else                s = ((const unsigned char*)in0)[i] != 0;
        }
        fired[i] = s ? 1 : 0;
        want = s;
    }
    unsigned long long m = __ballot(want);
    if (m) {
        int leader = __ffsll((long long)m) - 1;
        int base = 0;
        if (lane == leader) base = atomicAdd(&cnt[0], __popcll(m));
        base = __shfl(base, leader, 64);
        if (want) {
            int off = __popcll(m & ((1ull << (unsigned)lane) - 1ull));
            frontier0[base + off] = i;
        }
    }
}

// live = output target, or hidden target not yet fired
#define LIVE(SFB, TG) ({ int b_ = (TG) - NUM_INPUT; \
    (b_ >= NUM_HIDDEN) || !((SFB[b_ >> 5] >> (b_ & 31)) & 1u); })

// ---------------------------------------------------------------------------
// per-step scatter, path gated on LIVE edges (fcnt * unfired):
//   sparse: device atomics into acc, fired-skip, grid-stride.
//   dense : quarter-split LDS privatization (2 blocks/CU), partial ->
//           rep[(c*4+qtr)][.] (cached stores).
// block0 also snapshots unfired into the next step's slot.
// ---------------------------------------------------------------------------
__global__ __launch_bounds__(1024) void step_scatter_k(
    const int* __restrict__ fr, const int* __restrict__ cnt_cur,
    int* cnt_next, const int* __restrict__ unf_cur, int* unf_next,
    const int* __restrict__ targets, const float* __restrict__ weights,
    float* __restrict__ acc, float* __restrict__ rep,
    const unsigned* __restrict__ fbits)
{
    __shared__ float    lacc[QTR_SZ];            // 64.5 KB
    __shared__ unsigned sfb[FB_WORDS];           // 8 KB fired bitmap
    const int fcnt    = *cnt_cur;
    const int unfired = *unf_cur;
    const int tid  = threadIdx.x;
    if (blockIdx.x == 0 && tid == 0) {
        *cnt_next = 0;
        *unf_next = unfired;                     // snapshot for next step
    }
    if (fcnt == 0) return;

    if (!gate_dense(fcnt, unfired)) {
        // ---- sparse path (fired-hidden edges skipped), grid-stride ----
        const int nq = fcnt * (FAN_OUT / 4);
        if (blockIdx.x * 1024 >= nq) return;     // no work: skip sfb load
        for (int k = tid; k < FB_WORDS; k += 1024) sfb[k] = fbits[k];
        __syncthreads();
        const int stride = gridDim.x * 1024;
        for (int q = blockIdx.x * 1024 + tid; q < nq; q += stride) {
            int s  = fr[q >> 6];                 // wave-uniform source
            int j4 = (q & 63) << 2;
            const int base = s * FAN_OUT + j4;
            int4 tg = *(const int4*)(targets + base);
            const bool lx = LIVE(sfb, tg.x), ly = LIVE(sfb, tg.y);
            const bool lz = LIVE(sfb, tg.z), lw = LIVE(sfb, tg.w);
            if (lx | ly | lz | lw) {
                float4 wv = *(const float4*)(weights + base);
                float  st = (s < NUM_INPUT) ? 2.0f : 1.0f;
                if (lx) atomicAdd(&acc[tg.x], st * wv.x);
                if (ly) atomicAdd(&acc[tg.y], st * wv.y);
                if (lz) atomicAdd(&acc[tg.z], st * wv.z);
                if (lw) atomicAdd(&acc[tg.w], st * wv.w);
            }
        }
        return;
    }

    // ---- dense path ----
    const int chunks = calc_chunks(fcnt);
    const int c   = blockIdx.x & 127;            // chunk (same XCD for all qtr)
    const int qtr = blockIdx.x >> 7;             // 0..3
    if (c >= chunks) return;
    for (int k = tid; k < FB_WORDS; k += 1024) sfb[k] = fbits[k];
    const int base = NUM_INPUT + qtr * QTR_SZ;
    for (int k = tid; k < QTR_SZ / 4; k += 1024)
        ((float4*)lacc)[k] = make_float4(0.f, 0.f, 0.f, 0.f);
    __syncthreads();
    const int lo = (int)(((long long)fcnt * c)       / chunks);
    const int hi = (int)(((long long)fcnt * (c + 1)) / chunks);
    const int nq = (hi - lo) << 6;
    // x2 ILP: two independent edge-quad streams per iteration
    for (int q = tid; q < nq; q += 2048) {
        const int q2 = q + 1024;
        const bool hasB = q2 < nq;
        const int sA  = fr[lo + (q >> 6)];       // wave-uniform
        const int sB  = hasB ? fr[lo + (q2 >> 6)] : sA;
        const int ebA = sA * FAN_OUT + ((q  & 63) << 2);
        const int ebB = sB * FAN_OUT + ((q2 & 63) << 2);
        int4 tgA = *(const int4*)(targets + ebA);
        int4 tgB = *(const int4*)(targets + ebB);
        {
            int x = tgA.x - base; const bool kx = (unsigned)x < QTR_SZ && LIVE(sfb, tgA.x);
            int y = tgA.y - base; const bool ky = (unsigned)y < QTR_SZ && LIVE(sfb, tgA.y);
            int z = tgA.z - base; const bool kz = (unsigned)z < QTR_SZ && LIVE(sfb, tgA.z);
            int u = tgA.w - base; const bool ku = (unsigned)u < QTR_SZ && LIVE(sfb, tgA.w);
            if (kx | ky | kz | ku) {
                float4 wv = *(const float4*)(weights + ebA);
                const float st = (sA < NUM_INPUT) ? 2.0f : 1.0f;
                if (kx) atomicAdd(&lacc[x], st * wv.x);
                if (ky) atomicAdd(&lacc[y], st * wv.y);
                if (kz) atomicAdd(&lacc[z], st * wv.z);
                if (ku) atomicAdd(&lacc[u], st * wv.w);
            }
        }
        if (hasB) {
            int x = tgB.x - base; const bool kx = (unsigned)x < QTR_SZ && LIVE(sfb, tgB.x);
            int y = tgB.y - base; const bool ky = (unsigned)y < QTR_SZ && LIVE(sfb, tgB.y);
            int z = tgB.z - base; const bool kz = (unsigned)z < QTR_SZ && LIVE(sfb, tgB.z);
            int u = tgB.w - base; const bool ku = (unsigned)u < QTR_SZ && LIVE(sfb, tgB.w);
            if (kx | ky | kz | ku) {
                float4 wv = *(const float4*)(weights + ebB);
                const float st = (sB < NUM_INPUT) ? 2.0f : 1.0f;
                if (kx) atomicAdd(&lacc[x], st * wv.x);
                if (ky) atomicAdd(&lacc[y], st * wv.y);
                if (kz) atomicAdd(&lacc[z], st * wv.z);
                if (ku) atomicAdd(&lacc[u], st * wv.w);
            }
        }
    }
    __syncthreads();
    float4* out = (float4*)(rep + (size_t)((c << 2) + qtr) * QTR_SZ);
    for (int k = tid; k < QTR_SZ / 4; k += 1024) out[k] = ((float4*)lacc)[k];
}

// ---------------------------------------------------------------------------
// per-step update: 516 blocks x 128 = 66048 threads. Fired-hidden targets
// skipped (dead state). Sparse: consume acc. Dense: 8-stream cached reduce.
// Newly-fired hidden decrement the next-step unfired slot.
// ---------------------------------------------------------------------------
__global__ __launch_bounds__(128) void step_update_k(
    const float* __restrict__ rep, const int* __restrict__ cnt_cur,
    const int* __restrict__ unf_cur, int* unf_next,
    float* __restrict__ pot, float* __restrict__ acc,
    int* __restrict__ last_up, unsigned char* __restrict__ fired,
    int* __restrict__ frontier_next, int* __restrict__ cnt_next,
    float* __restrict__ out_f, const float* __restrict__ decay_tab, int t,
    unsigned* __restrict__ fbits)
{
    const int fcnt = *cnt_cur;
    if (fcnt == 0) return;
    const int unfired = *unf_cur;
    const int g = blockIdx.x * 128 + threadIdx.x;    // 0 .. 66047 exact
    const int lane = threadIdx.x & 63;
    bool w2 = false;
    const int n = NUM_INPUT + g;
    if (n >= OUT_START || !fired[n]) {               // skip dead fired-hidden
        float a;
        if (!gate_dense(fcnt, unfired)) {
            a = acc[n];
            if (a != 0.0f) acc[n] = 0.0f;
        } else {
            const int chunks = calc_chunks(fcnt);
            const int qtr = g / QTR_SZ;              // 0..3
            const int idx = g - qtr * QTR_SZ;
            const float* p0 = rep + (size_t)qtr * QTR_SZ + idx;
            float s0 = 0.f, s1 = 0.f, s2 = 0.f, s3 = 0.f;
            float s4 = 0.f, s5 = 0.f, s6 = 0.f, s7 = 0.f;
            int c = 0;
            for (; c + 7 < chunks; c += 8) {         // 8 independent streams
                s0 += p0[(size_t)(c + 0) * (4 * QTR_SZ)];
                s1 += p0[(size_t)(c + 1) * (4 * QTR_SZ)];
                s2 += p0[(size_t)(c + 2) * (4 * QTR_SZ)];
                s3 += p0[(size_t)(c + 3) * (4 * QTR_SZ)];
                s4 += p0[(size_t)(c + 4) * (4 * QTR_SZ)];
                s5 += p0[(size_t)(c + 5) * (4 * QTR_SZ)];
                s6 += p0[(size_t)(c + 6) * (4 * QTR_SZ)];
                s7 += p0[(size_t)(c + 7) * (4 * QTR_SZ)];
            }
            for (; c < chunks; ++c)
                s0 += p0[(size_t)c * (4 * QTR_SZ)];
            a = ((s0 + s1) + (s2 + s3)) + ((s4 + s5) + (s6 + s7));
        }
        if (a != 0.0f) {
            float p = pot[n] * decay_tab[t - last_up[n]] + a;
            last_up[n] = t;
            if (!fired[n] && p >= THRESH) {
                fired[n] = 1;
                if (n < OUT_START) {
                    p = 0.0f; w2 = true;
                    const int b = n - NUM_INPUT;
                    atomicOr(&fbits[b >> 5], 1u << (b & 31));
                } else out_f[n - OUT_START] = (float)t;
            }
            pot[n] = p;
        }
    }
    unsigned long long m = __ballot(w2);
    if (m) {
        int leader = __ffsll((long long)m) - 1;
        int base = 0;
        if (lane == leader) {
            const int cntw = __popcll(m);
            base = atomicAdd(cnt_next, cntw);
            atomicSub(unf_next, cntw);           // all w2 fires are hidden
        }
        base = __shfl(base, leader, 64);
        if (w2) {
            int off = __popcll(m & ((1ull << (unsigned)lane) - 1ull));
            frontier_next[base + off] = n;
        }
    }
}

// ---------------------------------------------------------------------------
// tail: one workgroup runs steps [T_BIG, 50), __syncthreads barriers,
// LDS-bitmap touched-list + LDS fired-bitmap skip, early exit; final out_pot.
// ---------------------------------------------------------------------------
__global__ __launch_bounds__(1024) void tail_k(
    float* __restrict__ pot, float* __restrict__ acc,
    int* __restrict__ last_up, unsigned char* __restrict__ fired,
    int* __restrict__ fr0, int* __restrict__ fr1, int* __restrict__ cnt,
    const int* __restrict__ targets, const float* __restrict__ weights,
    float* __restrict__ out_f, const float* __restrict__ decay_tab,
    const unsigned* __restrict__ fbits)
{
    __shared__ unsigned bm[BM_WORDS];
    __shared__ unsigned sfb[FB_WORDS];
    __shared__ int      lst[LIST_CAP];
    __shared__ int      lcnt, ovf;
    __shared__ float    sdecay[T_MAX + 1];
    const int tid = threadIdx.x;
    if (tid <= T_MAX) sdecay[tid] = decay_tab[tid];
    for (int k = tid; k < FB_WORDS; k += 1024) sfb[k] = fbits[k];

    for (int t = T_BIG; t < T_MAX; ++t) {
        const int cur = t & 1, nxt = cur ^ 1;
        for (int k = tid; k < BM_WORDS; k += 1024) bm[k] = 0u;
        if (tid == 0) { lcnt = 0; ovf = 0; cnt[nxt] = 0; }
        __syncthreads();
        const int fcnt = cnt[cur];
        if (fcnt == 0) break;
        const int* fr  = (cur == 0) ? fr0 : fr1;
        int*       frn = (cur == 0) ? fr1 : fr0;

        const int nq = fcnt * (FAN_OUT / 4);
        for (int q = tid; q < nq; q += 1024) {
            int s  = fr[q >> 6];
            int j4 = (q & 63) << 2;
            const int base = s * FAN_OUT + j4;
            int4 tg = *(const int4*)(targets + base);
            const bool lx = LIVE(sfb, tg.x), ly = LIVE(sfb, tg.y);
            const bool lz = LIVE(sfb, tg.z), lw = LIVE(sfb, tg.w);
            if (!(lx | ly | lz | lw)) continue;
            float4 wv = *(const float4*)(weights + base);
            float  st = (s < NUM_INPUT) ? 2.0f : 1.0f;
            #define EDGE(L, TG, WV) if (L) {                                  \
                atomicAdd(&acc[TG], st * (WV));                               \
                int b = (TG) - NUM_INPUT;                                     \
                unsigned bit = 1u << (b & 31);                                \
                unsigned old = atomicOr(&bm[b >> 5], bit);                    \
                if (!(old & bit)) {                                           \
                    int p_ = atomicAdd(&lcnt, 1);                             \
                    if (p_ < LIST_CAP) lst[p_] = (TG); else ovf = 1;          \
                } }
            EDGE(lx, tg.x, wv.x); EDGE(ly, tg.y, wv.y);
            EDGE(lz, tg.z, wv.z); EDGE(lw, tg.w, wv.w);
            #undef EDGE
        }
        __syncthreads();

        const int M = lcnt;
        const bool full = (ovf != 0);
        const int lo = full ? (NUM_INPUT + tid) : tid;
        const int hi = full ? N_TOTAL : M;
        for (int k = lo; k < hi; k += 1024) {
            const int n = full ? k : lst[k];
            if (n < OUT_START && fired[n]) continue;   // dead state
            float a = __hip_atomic_load(&acc[n], __ATOMIC_RELAXED,
                                        __HIP_MEMORY_SCOPE_AGENT);
            if (a != 0.0f) {
                __hip_atomic_store(&acc[n], 0.0f, __ATOMIC_RELAXED,
                                   __HIP_MEMORY_SCOPE_AGENT);
                float p = pot[n] * sdecay[t - last_up[n]] + a;
                last_up[n] = t;
                if (!fired[n] && p >= THRESH) {
                    fired[n] = 1;
                    if (n < OUT_START) {
                        p = 0.0f;
                        int pos = atomicAdd(&cnt[nxt], 1);
                        frn[pos] = n;
                        const int b = n - NUM_INPUT;
                        atomicOr(&sfb[b >> 5], 1u << (b & 31));
                    } else out_f[n - OUT_START] = (float)t;
                }
                pot[n] = p;
            }
        }
        __syncthreads();
    }

    __syncthreads();
    for (int i = tid; i < NUM_OUTPUT; i += 1024) {
        int n = OUT_START + i;
        out_f[NUM_OUTPUT + i] = pot[n] * sdecay[T_MAX - last_up[n]];
    }
}

extern "C" void kernel_launch(void* const* d_in, const int* in_sizes, int n_in,
                              void* d_out, int out_size, void* d_ws, size_t ws_size,
                              hipStream_t stream) {
    const void*  in_spikes = d_in[0];
    const float* weights   = (const float*)d_in[1];
    const int*   targets   = (const int*)d_in[2];
    float*       out_f     = (float*)d_out;

    char* w = (char*)d_ws;
    int*      cnt       = (int*)w;               // [0],[1] frontier; [2],[3] unfired
    float*    decay_tab = (float*)(w + 256);     // 51 floats
    float*    pot       = (float*)(w + 512);
    float*    acc       = pot + N_TOTAL;
    int*      last_up   = (int*)(acc + N_TOTAL);
    int*      fr0       = last_up + N_TOTAL;
    int*      fr1       = fr0 + N_TOTAL;
    unsigned* fbits     = (unsigned*)(fr1 + N_TOTAL);
    unsigned char* fired = (unsigned char*)(fbits + FB_WORDS);
    size_t base_bytes = (size_t)((char*)(fired + N_TOTAL) - w);
    size_t rep_off    = (base_bytes + 255) & ~(size_t)255;
    float* rep        = (float*)(w + rep_off);

    (void)hipMemsetAsync(cnt, 0, 16, stream);
    init_k<<<266, 256, 0, stream>>>((const unsigned int*)in_spikes,
                                    pot, acc, last_up, fired,
                                    fr0, cnt, out_f, decay_tab, fbits);

    int* fr[2] = {fr0, fr1};
    for (int t = 0; t < T_BIG; ++t) {
        const int cur = t & 1, nxt = cur ^ 1;
        const int ucur = 2 + (t & 1), unxt = 2 + ((t + 1) & 1);
        step_scatter_k<<<4 * N_CHUNK, 1024, 0, stream>>>(
            fr[cur], &cnt[cur], &cnt[nxt], &cnt[ucur], &cnt[unxt],
            targets, weights, acc, rep, fbits);
        step_update_k<<<516, 128, 0, stream>>>(
            rep, &cnt[cur], &cnt[ucur], &cnt[unxt], pot, acc, last_up, fired,
            fr[nxt], &cnt[nxt], out_f, decay_tab, t, fbits);
    }
    tail_k<<<1, 1024, 0, stream>>>(pot, acc, last_up, fired, fr0, fr1, cnt,
                                   targets, weights, out_f, decay_tab, fbits);
}

// Round 14
// 264.371 us; speedup vs baseline: 1.2568x; 1.2568x over previous
//
#include <hip/hip_runtime.h>
#include <math.h>

#define N_TOTAL    68096
#define NUM_INPUT  2048
#define NUM_OUTPUT 512
#define OUT_START  67584   // NUM_INPUT + NUM_HIDDEN
#define N_TGT      66048   // N_TOTAL - NUM_INPUT
#define NUM_HIDDEN 65536
#define FB_WORDS   2048    // 65536 hidden bits
#define FAN_OUT    256
#define THRESH     0.3f
#define T_MAX      50
#define T_BIG      12      // steps [0, T_BIG) multi-launch; rest in tail_k
#define BM_WORDS   2064    // ceil(66048 / 32)
#define LIST_CAP   12288

#define QTR_SZ     16512   // N_TGT / 4 targets per quarter
#define N_CHUNK    128     // max frontier chunks in dense mode
#define DENSE_THR  6000    // frontier size at/above which dense path engages
// NOTE: r10-r13 experiments (live-edge gate fcnt*unfired, nontemporal rep,
// 8-stream reduce) ALL regressed vs this configuration (265 -> 316..335us).
// This file is the r9 best-known config restored verbatim.

// Once a HIDDEN neuron fires, its pot/last_update are dead state (outputs of
// the problem are out_times + output-pot only; fired neurons can never fire
// again). Edges into fired-hidden targets are skipped; fired-hidden targets
// are skipped in update sweeps. fbits = hidden-fired bitmap.

__device__ __forceinline__ int calc_chunks(int fcnt) {
    int c = fcnt >> 7;                           // ~128 sources per chunk
    if (c < 1) c = 1;
    if (c > N_CHUNK) c = N_CHUNK;
    return c;
}

// ---------------------------------------------------------------------------
// init: decay table, state arrays, fbits, frontier0 from input spikes.
// Input-bool dtype (int32/float32/uint8) detected per-block (2 KB scan).
// ---------------------------------------------------------------------------
__global__ __launch_bounds__(256) void init_k(
    const unsigned int* __restrict__ in0,
    float* pot, float* acc, int* last_up, unsigned char* fired,
    int* frontier0, int* cnt, float* out_f, float* decay_tab,
    unsigned* fbits)
{
    __shared__ int sF, sG;
    const int tid = threadIdx.x;
    if (tid == 0) { sF = 0; sG = 0; }
    __syncthreads();
    for (int k = tid; k < 512; k += 256) {       // 2048 bytes: safe all modes
        unsigned int v = in0[k];
        if (v == 0x3F800000u) atomicAdd(&sF, 1);
        else if (v > 1u)      sG = 1;            // benign race
    }
    __syncthreads();
    const int mode = (sF >= 8) ? 1 : (sG ? 2 : 0);

    const int i = blockIdx.x * 256 + tid;
    const int lane = tid & 63;
    if (i <= T_MAX) {
        float base = expf(-0.05f);               // exact validated path
        decay_tab[i] = (float)pow((double)base, (double)i);
    }
    if (i < NUM_OUTPUT) out_f[i] = -1.0f;
    if (i < FB_WORDS)   fbits[i] = 0u;
    bool want = false;
    if (i < N_TOTAL) {
        pot[i] = 0.0f;
        acc[i] = 0.0f;
        last_up[i] = 0;
        bool s = false;
        if (i < NUM_INPUT) {
            if (mode == 0)      s = ((const int*)in0)[i] != 0;
            else if (mode == 1) s = ((const float*)in0)[i] != 0.0f;
            else                s = ((const unsigned char*)in0)[i] != 0;
        }
        fired[i] = s ? 1 : 0;
        want = s;
    }
    unsigned long long m = __ballot(want);
    if (m) {
        int leader = __ffsll((long long)m) - 1;
        int base = 0;
        if (lane == leader) base = atomicAdd(&cnt[0], __popcll(m));
        base = __shfl(base, leader, 64);
        if (want) {
            int off = __popcll(m & ((1ull << (unsigned)lane) - 1ull));
            frontier0[base + off] = i;
        }
    }
}

// live = output target, or hidden target not yet fired
#define LIVE(SFB, TG) ({ int b_ = (TG) - NUM_INPUT; \
    (b_ >= NUM_HIDDEN) || !((SFB[b_ >> 5] >> (b_ & 31)) & 1u); })

// ---------------------------------------------------------------------------
// per-step scatter, path chosen on device:
//   fcnt <  DENSE_THR : device atomics into acc (sparse), fired-skip.
//     grid 512x1024 covers max sparse quads (384K) -> one quad per thread,
//     blocks beyond nq exit before touching LDS.
//   fcnt >= DENSE_THR : dense. quarter-split (lacc 64.5 KB + sfb 8 KB ->
//     2 blocks/CU, 32 waves/CU latency hiding). chunk c = bid&127,
//     qtr = bid>>7; the 4 quarter-blocks of a chunk share an XCD (128%8==0)
//     so their common edge reads hit local L2. Partial -> rep[(c*4+qtr)][.].
// ---------------------------------------------------------------------------
__global__ __launch_bounds__(1024) void step_scatter_k(
    const int* __restrict__ fr, const int* __restrict__ cnt_cur,
    int* cnt_next,
    const int* __restrict__ targets, const float* __restrict__ weights,
    float* __restrict__ acc, float* __restrict__ rep,
    const unsigned* __restrict__ fbits)
{
    __shared__ float    lacc[QTR_SZ];            // 64.5 KB
    __shared__ unsigned sfb[FB_WORDS];           // 8 KB fired bitmap
    const int fcnt = *cnt_cur;
    const int tid  = threadIdx.x;
    if (blockIdx.x == 0 && tid == 0) *cnt_next = 0;
    if (fcnt == 0) return;

    if (fcnt < DENSE_THR) {
        // ---- sparse path (fired-hidden edges skipped) ----
        const int nq = fcnt * (FAN_OUT / 4);
        const int q  = blockIdx.x * 1024 + tid;
        if (blockIdx.x * 1024 >= nq) return;     // no work: skip sfb load
        for (int k = tid; k < FB_WORDS; k += 1024) sfb[k] = fbits[k];
        __syncthreads();
        if (q < nq) {
            int s  = fr[q >> 6];                 // wave-uniform source
            int j4 = (q & 63) << 2;
            const int base = s * FAN_OUT + j4;
            int4 tg = *(const int4*)(targets + base);
            const bool lx = LIVE(sfb, tg.x), ly = LIVE(sfb, tg.y);
            const bool lz = LIVE(sfb, tg.z), lw = LIVE(sfb, tg.w);
            if (lx | ly | lz | lw) {
                float4 wv = *(const float4*)(weights + base);
                float  st = (s < NUM_INPUT) ? 2.0f : 1.0f;
                if (lx) atomicAdd(&acc[tg.x], st * wv.x);
                if (ly) atomicAdd(&acc[tg.y], st * wv.y);
                if (lz) atomicAdd(&acc[tg.z], st * wv.z);
                if (lw) atomicAdd(&acc[tg.w], st * wv.w);
            }
        }
        return;
    }

    // ---- dense path ----
    const int chunks = calc_chunks(fcnt);
    const int c   = blockIdx.x & 127;            // chunk (same XCD for all qtr)
    const int qtr = blockIdx.x >> 7;             // 0..3
    if (c >= chunks) return;
    for (int k = tid; k < FB_WORDS; k += 1024) sfb[k] = fbits[k];
    const int base = NUM_INPUT + qtr * QTR_SZ;
    for (int k = tid; k < QTR_SZ / 4; k += 1024)
        ((float4*)lacc)[k] = make_float4(0.f, 0.f, 0.f, 0.f);
    __syncthreads();
    const int lo = (int)(((long long)fcnt * c)       / chunks);
    const int hi = (int)(((long long)fcnt * (c + 1)) / chunks);
    const int nq = (hi - lo) << 6;
    // x2 ILP: two independent edge-quad streams per iteration
    for (int q = tid; q < nq; q += 2048) {
        const int q2 = q + 1024;
        const bool hasB = q2 < nq;
        const int sA  = fr[lo + (q >> 6)];       // wave-uniform
        const int sB  = hasB ? fr[lo + (q2 >> 6)] : sA;
        const int ebA = sA * FAN_OUT + ((q  & 63) << 2);
        const int ebB = sB * FAN_OUT + ((q2 & 63) << 2);
        int4 tgA = *(const int4*)(targets + ebA);
        int4 tgB = *(const int4*)(targets + ebB);
        {
            int x = tgA.x - base; const bool kx = (unsigned)x < QTR_SZ && LIVE(sfb, tgA.x);
            int y = tgA.y - base; const bool ky = (unsigned)y < QTR_SZ && LIVE(sfb, tgA.y);
            int z = tgA.z - base; const bool kz = (unsigned)z < QTR_SZ && LIVE(sfb, tgA.z);
            int u = tgA.w - base; const bool ku = (unsigned)u < QTR_SZ && LIVE(sfb, tgA.w);
            if (kx | ky | kz | ku) {
                float4 wv = *(const float4*)(weights + ebA);
                const float st = (sA < NUM_INPUT) ? 2.0f : 1.0f;
                if (kx) atomicAdd(&lacc[x], st * wv.x);
                if (ky) atomicAdd(&lacc[y], st * wv.y);
                if (kz) atomicAdd(&lacc[z], st * wv.z);
                if (ku) atomicAdd(&lacc[u], st * wv.w);
            }
        }
        if (hasB) {
            int x = tgB.x - base; const bool kx = (unsigned)x < QTR_SZ && LIVE(sfb, tgB.x);
            int y = tgB.y - base; const bool ky = (unsigned)y < QTR_SZ && LIVE(sfb, tgB.y);
            int z = tgB.z - base; const bool kz = (unsigned)z < QTR_SZ && LIVE(sfb, tgB.z);
            int u = tgB.w - base; const bool ku = (unsigned)u < QTR_SZ && LIVE(sfb, tgB.w);
            if (kx | ky | kz | ku) {
                float4 wv = *(const float4*)(weights + ebB);
                const float st = (sB < NUM_INPUT) ? 2.0f : 1.0f;
                if (kx) atomicAdd(&lacc[x], st * wv.x);
                if (ky) atomicAdd(&lacc[y], st * wv.y);
                if (kz) atomicAdd(&lacc[z], st * wv.z);
                if (ku) atomicAdd(&lacc[u], st * wv.w);
            }
        }
    }
    __syncthreads();
    float4* out = (float4*)(rep + (size_t)((c << 2) + qtr) * QTR_SZ);
    for (int k = tid; k < QTR_SZ / 4; k += 1024) out[k] = ((float4*)lacc)[k];
}

// ---------------------------------------------------------------------------
// per-step update: 516 blocks x 128 = 66048 threads. Fired-hidden targets
// skipped outright (dead state). Sparse: consume acc. Dense: reduce partials.
// ---------------------------------------------------------------------------
__global__ __launch_bounds__(128) void step_update_k(
    const float* __restrict__ rep, const int* __restrict__ cnt_cur,
    float* __restrict__ pot, float* __restrict__ acc,
    int* __restrict__ last_up, unsigned char* __restrict__ fired,
    int* __restrict__ frontier_next, int* __restrict__ cnt_next,
    float* __restrict__ out_f, const float* __restrict__ decay_tab, int t,
    unsigned* __restrict__ fbits)
{
    const int fcnt = *cnt_cur;
    if (fcnt == 0) return;
    const int g = blockIdx.x * 128 + threadIdx.x;    // 0 .. 66047 exact
    const int lane = threadIdx.x & 63;
    bool w2 = false;
    const int n = NUM_INPUT + g;
    if (n >= OUT_START || !fired[n]) {               // skip dead fired-hidden
        float a;
        if (fcnt < DENSE_THR) {
            a = acc[n];
            if (a != 0.0f) acc[n] = 0.0f;
        } else {
            const int chunks = calc_chunks(fcnt);
            const int qtr = g / QTR_SZ;              // 0..3
            const int idx = g - qtr * QTR_SZ;
            const float* p0 = rep + (size_t)qtr * QTR_SZ + idx;
            float a0 = 0.f, a1 = 0.f, a2 = 0.f, a3 = 0.f;
            int c = 0;
            for (; c + 3 < chunks; c += 4) {
                a0 += p0[(size_t)(c + 0) * (4 * QTR_SZ)];
                a1 += p0[(size_t)(c + 1) * (4 * QTR_SZ)];
                a2 += p0[(size_t)(c + 2) * (4 * QTR_SZ)];
                a3 += p0[(size_t)(c + 3) * (4 * QTR_SZ)];
            }
            for (; c < chunks; ++c)
                a0 += p0[(size_t)c * (4 * QTR_SZ)];
            a = (a0 + a1) + (a2 + a3);
        }
        if (a != 0.0f) {
            float p = pot[n] * decay_tab[t - last_up[n]] + a;
            last_up[n] = t;
            if (!fired[n] && p >= THRESH) {
                fired[n] = 1;
                if (n < OUT_START) {
                    p = 0.0f; w2 = true;
                    const int b = n - NUM_INPUT;
                    atomicOr(&fbits[b >> 5], 1u << (b & 31));
                } else out_f[n - OUT_START] = (float)t;
            }
            pot[n] = p;
        }
    }
    unsigned long long m = __ballot(w2);
    if (m) {
        int leader = __ffsll((long long)m) - 1;
        int base = 0;
        if (lane == leader) base = atomicAdd(cnt_next, __popcll(m));
        base = __shfl(base, leader, 64);
        if (w2) {
            int off = __popcll(m & ((1ull << (unsigned)lane) - 1ull));
            frontier_next[base + off] = n;
        }
    }
}

// ---------------------------------------------------------------------------
// tail: one workgroup runs steps [T_BIG, 50), __syncthreads barriers,
// LDS-bitmap touched-list + LDS fired-bitmap skip, early exit; final out_pot.
// ---------------------------------------------------------------------------
__global__ __launch_bounds__(1024) void tail_k(
    float* __restrict__ pot, float* __restrict__ acc,
    int* __restrict__ last_up, unsigned char* __restrict__ fired,
    int* __restrict__ fr0, int* __restrict__ fr1, int* __restrict__ cnt,
    const int* __restrict__ targets, const float* __restrict__ weights,
    float* __restrict__ out_f, const float* __restrict__ decay_tab,
    const unsigned* __restrict__ fbits)
{
    __shared__ unsigned bm[BM_WORDS];
    __shared__ unsigned sfb[FB_WORDS];
    __shared__ int      lst[LIST_CAP];
    __shared__ int      lcnt, ovf;
    __shared__ float    sdecay[T_MAX + 1];
    const int tid = threadIdx.x;
    if (tid <= T_MAX) sdecay[tid] = decay_tab[tid];
    for (int k = tid; k < FB_WORDS; k += 1024) sfb[k] = fbits[k];

    for (int t = T_BIG; t < T_MAX; ++t) {
        const int cur = t & 1, nxt = cur ^ 1;
        for (int k = tid; k < BM_WORDS; k += 1024) bm[k] = 0u;
        if (tid == 0) { lcnt = 0; ovf = 0; cnt[nxt] = 0; }
        __syncthreads();
        const int fcnt = cnt[cur];
        if (fcnt == 0) break;
        const int* fr  = (cur == 0) ? fr0 : fr1;
        int*       frn = (cur == 0) ? fr1 : fr0;

        const int nq = fcnt * (FAN_OUT / 4);
        for (int q = tid; q < nq; q += 1024) {
            int s  = fr[q >> 6];
            int j4 = (q & 63) << 2;
            const int base = s * FAN_OUT + j4;
            int4 tg = *(const int4*)(targets + base);
            const bool lx = LIVE(sfb, tg.x), ly = LIVE(sfb, tg.y);
            const bool lz = LIVE(sfb, tg.z), lw = LIVE(sfb, tg.w);
            if (!(lx | ly | lz | lw)) continue;
            float4 wv = *(const float4*)(weights + base);
            float  st = (s < NUM_INPUT) ? 2.0f : 1.0f;
            #define EDGE(L, TG, WV) if (L) {                                  \
                atomicAdd(&acc[TG], st * (WV));                               \
                int b = (TG) - NUM_INPUT;                                     \
                unsigned bit = 1u << (b & 31);                                \
                unsigned old = atomicOr(&bm[b >> 5], bit);                    \
                if (!(old & bit)) {                                           \
                    int p_ = atomicAdd(&lcnt, 1);                             \
                    if (p_ < LIST_CAP) lst[p_] = (TG); else ovf = 1;          \
                } }
            EDGE(lx, tg.x, wv.x); EDGE(ly, tg.y, wv.y);
            EDGE(lz, tg.z, wv.z); EDGE(lw, tg.w, wv.w);
            #undef EDGE
        }
        __syncthreads();

        const int M = lcnt;
        const bool full = (ovf != 0);
        const int lo = full ? (NUM_INPUT + tid) : tid;
        const int hi = full ? N_TOTAL : M;
        for (int k = lo; k < hi; k += 1024) {
            const int n = full ? k : lst[k];
            if (n < OUT_START && fired[n]) continue;   // dead state
            float a = __hip_atomic_load(&acc[n], __ATOMIC_RELAXED,
                                        __HIP_MEMORY_SCOPE_AGENT);
            if (a != 0.0f) {
                __hip_atomic_store(&acc[n], 0.0f, __ATOMIC_RELAXED,
                                   __HIP_MEMORY_SCOPE_AGENT);
                float p = pot[n] * sdecay[t - last_up[n]] + a;
                last_up[n] = t;
                if (!fired[n] && p >= THRESH) {
                    fired[n] = 1;
                    if (n < OUT_START) {
                        p = 0.0f;
                        int pos = atomicAdd(&cnt[nxt], 1);
                        frn[pos] = n;
                        const int b = n - NUM_INPUT;
                        atomicOr(&sfb[b >> 5], 1u << (b & 31));
                    } else out_f[n - OUT_START] = (float)t;
                }
                pot[n] = p;
            }
        }
        __syncthreads();
    }

    __syncthreads();
    for (int i = tid; i < NUM_OUTPUT; i += 1024) {
        int n = OUT_START + i;
        out_f[NUM_OUTPUT + i] = pot[n] * sdecay[T_MAX - last_up[n]];
    }
}

extern "C" void kernel_launch(void* const* d_in, const int* in_sizes, int n_in,
                              void* d_out, int out_size, void* d_ws, size_t ws_size,
                              hipStream_t stream) {
    const void*  in_spikes = d_in[0];
    const float* weights   = (const float*)d_in[1];
    const int*   targets   = (const int*)d_in[2];
    float*       out_f     = (float*)d_out;

    char* w = (char*)d_ws;
    int*      cnt       = (int*)w;               // [0],[1] frontier counts
    float*    decay_tab = (float*)(w + 256);     // 51 floats
    float*    pot       = (float*)(w + 512);
    float*    acc       = pot + N_TOTAL;
    int*      last_up   = (int*)(acc + N_TOTAL);
    int*      fr0       = last_up + N_TOTAL;
    int*      fr1       = fr0 + N_TOTAL;
    unsigned* fbits     = (unsigned*)(fr1 + N_TOTAL);
    unsigned char* fired = (unsigned char*)(fbits + FB_WORDS);
    size_t base_bytes = (size_t)((char*)(fired + N_TOTAL) - w);
    size_t rep_off    = (base_bytes + 255) & ~(size_t)255;
    float* rep        = (float*)(w + rep_off);

    (void)hipMemsetAsync(cnt, 0, 16, stream);
    init_k<<<266, 256, 0, stream>>>((const unsigned int*)in_spikes,
                                    pot, acc, last_up, fired,
                                    fr0, cnt, out_f, decay_tab, fbits);

    int* fr[2] = {fr0, fr1};
    for (int t = 0; t < T_BIG; ++t) {
        const int cur = t & 1, nxt = cur ^ 1;
        step_scatter_k<<<4 * N_CHUNK, 1024, 0, stream>>>(
            fr[cur], &cnt[cur], &cnt[nxt], targets, weights, acc, rep, fbits);
        step_update_k<<<516, 128, 0, stream>>>(
            rep, &cnt[cur], pot, acc, last_up, fired,
            fr[nxt], &cnt[nxt], out_f, decay_tab, t, fbits);
    }
    tail_k<<<1, 1024, 0, stream>>>(pot, acc, last_up, fired, fr0, fr1, cnt,
                                   targets, weights, out_f, decay_tab, fbits);
}